// Round 1
// baseline (53.614 us; speedup 1.0000x reference)
//
#include <hip/hip_runtime.h>
#include <stdint.h>

#define OUT_ROIS 128
#define FG_MAX 32
#define BG_PID_F 5532.0f

// ---------------- Kernel 1: per-roi max/argmax IoU + classification ----------------
// Each block = 256 rois. gt boxes (<=256) staged in LDS. Writes per-roi packed
// code = (argmax<<2)|cls (cls: 0 neither, 1 fg, 2 bg) and per-block fg/bg counts.
__global__ __launch_bounds__(256) void ptl_classify(
    const float* __restrict__ all_rois, const float* __restrict__ gt,
    int R, int G, int N,
    uint16_t* __restrict__ code, int* __restrict__ blkF, int* __restrict__ blkB)
{
#pragma clang fp contract(off)
    __shared__ float gx1[256], gy1[256], gx2[256], gy2[256], gar[256];
    __shared__ int cF, cB;
    const int t = threadIdx.x;
    const int b = blockIdx.x;

    if (t < G) {
        const float* p = gt + (size_t)t * 6;
        float a = p[0], bb = p[1], c = p[2], d = p[3];
        gx1[t] = a; gy1[t] = bb; gx2[t] = c; gy2[t] = d;
        gar[t] = ((c - a) + 1.0f) * ((d - bb) + 1.0f);
    }
    if (t == 0) { cF = 0; cB = 0; }
    __syncthreads();

    const int i = b * 256 + t;
    if (i < N) {
        float x1, y1, x2, y2;
        if (i < R) {
            const float* p = all_rois + (size_t)i * 5;
            x1 = p[1]; y1 = p[2]; x2 = p[3]; y2 = p[4];
        } else {
            const float* p = gt + (size_t)(i - R) * 6;
            x1 = p[0]; y1 = p[1]; x2 = p[2]; y2 = p[3];
        }
        const float A = ((x2 - x1) + 1.0f) * ((y2 - y1) + 1.0f);
        float mx = -1.0f;
        int amax = 0;
#pragma unroll 4
        for (int j = 0; j < G; ++j) {
            float iw = (fminf(x2, gx2[j]) - fmaxf(x1, gx1[j])) + 1.0f;
            float ih = (fminf(y2, gy2[j]) - fmaxf(y1, gy1[j])) + 1.0f;
            iw = fmaxf(iw, 0.0f);
            ih = fmaxf(ih, 0.0f);
            float inter = iw * ih;
            // IEEE-correct division: bit-matches numpy; strict > = first-occurrence argmax
            float iou = inter / ((A + gar[j]) - inter);
            if (iou > mx) { mx = iou; amax = j; }
        }
        int cls = 0;
        if (mx >= 0.5f) cls = 1;
        else if (mx >= 0.1f) cls = 2;
        code[i] = (uint16_t)((amax << 2) | cls);
        if (cls == 1) atomicAdd(&cF, 1);
        else if (cls == 2) atomicAdd(&cB, 1);
    }
    __syncthreads();
    if (t == 0) { blkF[b] = cF; blkB[b] = cB; }
}

// ---------------- Kernel 2: ordered first-k selection + epilogue ----------------
// Single block, 256 threads. Block counts -> totals -> num_fg/num_bg; then an
// ordered compaction over only the blocks that contribute to the first
// num_fg fg / num_bg bg (early exit). Epilogue: 128 threads emit all outputs.
__global__ __launch_bounds__(256) void ptl_select_emit(
    const float* __restrict__ all_rois, const float* __restrict__ gt,
    const uint16_t* __restrict__ code,
    const int* __restrict__ blkF, const int* __restrict__ blkB,
    int R, int G, int N, int nblocks,
    float* __restrict__ out)
{
#pragma clang fp contract(off)
    __shared__ int sF[1024], sB[1024];
    __shared__ int keep[OUT_ROIS];
    __shared__ int wF[4], wB[4];
    __shared__ int nums[2];
    const int t = threadIdx.x;

    for (int i = t; i < nblocks; i += 256) { sF[i] = blkF[i]; sB[i] = blkB[i]; }
    if (t < OUT_ROIS) keep[t] = 0;   // reference: unfilled slots index roi 0
    __syncthreads();

    if (t == 0) {
        int tf = 0, tb = 0;
        for (int i = 0; i < nblocks; ++i) { tf += sF[i]; tb += sB[i]; }
        int nf = tf < FG_MAX ? tf : FG_MAX;
        int rem = OUT_ROIS - nf;
        int nb = tb < rem ? tb : rem;
        nums[0] = nf; nums[1] = nb;
    }
    __syncthreads();
    const int num_fg = nums[0];
    const int num_bg = nums[1];

    const int lane = t & 63;
    const int w = t >> 6;
    int fgBase = 0, bgBase = 0;
    for (int b = 0; b < nblocks; ++b) {
        const int cFv = sF[b], cBv = sB[b];
        const bool needF = (fgBase < num_fg) && (cFv > 0);
        const bool needB = (bgBase < num_bg) && (cBv > 0);
        if (needF || needB) {   // uniform across block
            const int i = b * 256 + t;
            const int c = (i < N) ? (int)(code[i] & 3) : 0;
            const bool isF = (c == 1), isB = (c == 2);
            unsigned long long mF = __ballot(isF);
            unsigned long long mB = __ballot(isB);
            if (lane == 0) { wF[w] = __popcll(mF); wB[w] = __popcll(mB); }
            __syncthreads();
            int offF = fgBase, offB = bgBase;
            for (int ww = 0; ww < w; ++ww) { offF += wF[ww]; offB += wB[ww]; }
            const unsigned long long lowmask = (1ull << lane) - 1ull;
            const int pF = offF + __popcll(mF & lowmask);
            const int pB = offB + __popcll(mB & lowmask);
            if (isF && pF < num_fg) keep[pF] = i;
            if (isB && pB < num_bg) keep[num_fg + pB] = i;
            __syncthreads();
        }
        fgBase += cFv; bgBase += cBv;
        if (fgBase >= num_fg && bgBase >= num_bg) break;
    }
    __syncthreads();

    if (t < OUT_ROIS) {
        const int s = t;
        const int k = keep[s];
        const bool isfg = s < num_fg;
        float x1, y1, x2, y2;
        if (k < R) {
            const float* p = all_rois + (size_t)k * 5;
            x1 = p[1]; y1 = p[2]; x2 = p[3]; y2 = p[4];
        } else {
            const float* p = gt + (size_t)(k - R) * 6;
            x1 = p[0]; y1 = p[1]; x2 = p[2]; y2 = p[3];
        }
        const int amax = (int)(code[k] >> 2);
        const float* g = gt + (size_t)amax * 6;
        const float gx1v = g[0], gy1v = g[1], gx2v = g[2], gy2v = g[3];
        const float label = isfg ? g[4] : 0.0f;
        const float pid = isfg ? g[5] : BG_PID_F;

        // rois [128,5] @ 0
        float* ro = out + (size_t)s * 5;
        ro[0] = 0.0f; ro[1] = x1; ro[2] = y1; ro[3] = x2; ro[4] = y2;
        // labels [128] @ 640, pids [128] @ 768 (int-valued floats)
        out[640 + s] = (float)(int)label;
        out[768 + s] = (float)(int)pid;

        // bbox_transform + (t - 0)/std, matching reference op order
        const float ew = (x2 - x1) + 1.0f, eh = (y2 - y1) + 1.0f;
        const float ecx = x1 + 0.5f * ew, ecy = y1 + 0.5f * eh;
        const float gw = (gx2v - gx1v) + 1.0f, gh = (gy2v - gy1v) + 1.0f;
        const float gcx = gx1v + 0.5f * gw, gcy = gy1v + 0.5f * gh;
        float tv[4];
        tv[0] = ((gcx - ecx) / ew) / 0.1f;
        tv[1] = ((gcy - ecy) / eh) / 0.1f;
        tv[2] = logf(gw / ew) / 0.2f;
        tv[3] = logf(gh / eh) / 0.2f;

        const int cls = (int)roundf(label);
        const float on = (label > 0.0f) ? 1.0f : 0.0f;

        float* bt = out + 896  + (size_t)s * 8;
        float* bi = out + 1920 + (size_t)s * 8;
        float* bo = out + 2944 + (size_t)s * 8;
#pragma unroll
        for (int cc = 0; cc < 2; ++cc) {
            const float sel = (cc == cls) ? on : 0.0f;
#pragma unroll
            for (int j = 0; j < 4; ++j) {
                bt[cc * 4 + j] = sel * tv[j];
                bi[cc * 4 + j] = sel;
                bo[cc * 4 + j] = sel;
            }
        }
    }
}

extern "C" void kernel_launch(void* const* d_in, const int* in_sizes, int n_in,
                              void* d_out, int out_size, void* d_ws, size_t ws_size,
                              hipStream_t stream) {
    const float* all_rois = (const float*)d_in[0];
    const float* gt       = (const float*)d_in[1];
    const int R = in_sizes[0] / 5;
    const int G = in_sizes[1] / 6;
    const int N = R + G;
    const int nblocks = (N + 255) / 256;   // 513 for this problem (<=1024 supported)

    uint16_t* code = (uint16_t*)d_ws;
    size_t codeBytes = (((size_t)N * 2) + 3) & ~(size_t)3;
    int* blkF = (int*)((char*)d_ws + codeBytes);
    int* blkB = blkF + nblocks;
    float* out = (float*)d_out;

    ptl_classify<<<nblocks, 256, 0, stream>>>(all_rois, gt, R, G, N, code, blkF, blkB);
    ptl_select_emit<<<1, 256, 0, stream>>>(all_rois, gt, code, blkF, blkB, R, G, N, nblocks, out);
}

// Round 2
// 40.937 us; speedup vs baseline: 1.3097x; 1.3097x over previous
//
#include <hip/hip_runtime.h>
#include <stdint.h>

#define OUT_ROIS 128
#define FG_MAX 32
#define BG_PID_F 5532.0f
#define MAXCH 2304            // max 64-roi chunks supported (N <= 147456)

// ---------------- Kernel 1: per-roi max/argmax IoU + classification ----------------
// Block = 64 rois x 4 waves; wave w covers gt range [G*w/4, G*(w+1)/4) with a
// uniform-j loop (LDS broadcast reads, conflict-free). Partial (max,argmax)
// combined in wave order with strict > == numpy first-occurrence argmax.
__global__ __launch_bounds__(256) void ptl_classify(
    const float* __restrict__ all_rois, const float* __restrict__ gt,
    int R, int G, int N,
    uint16_t* __restrict__ code, int* __restrict__ blkF, int* __restrict__ blkB)
{
#pragma clang fp contract(off)
    __shared__ float gx1[256], gy1[256], gx2[256], gy2[256], gar[256];
    __shared__ float smx[4][64];
    __shared__ int   sam[4][64];
    const int t = threadIdx.x;
    const int w = t >> 6, lane = t & 63;

    if (t < G) {
        const float* p = gt + (size_t)t * 6;
        float a = p[0], bb = p[1], c = p[2], d = p[3];
        gx1[t] = a; gy1[t] = bb; gx2[t] = c; gy2[t] = d;
        gar[t] = ((c - a) + 1.0f) * ((d - bb) + 1.0f);
    }
    __syncthreads();

    const int i = blockIdx.x * 64 + lane;
    float x1, y1, x2, y2;
    if (i < N) {
        if (i < R) {
            const float* p = all_rois + (size_t)i * 5;
            x1 = p[1]; y1 = p[2]; x2 = p[3]; y2 = p[4];
        } else {
            const float* p = gt + (size_t)(i - R) * 6;
            x1 = p[0]; y1 = p[1]; x2 = p[2]; y2 = p[3];
        }
    } else { x1 = 0.0f; y1 = 0.0f; x2 = -2.0f; y2 = -2.0f; }
    const float A = ((x2 - x1) + 1.0f) * ((y2 - y1) + 1.0f);

    const int jbeg = (G * w) >> 2;
    const int jend = (G * (w + 1)) >> 2;
    float mx = -1.0f;
    int am = 0;
#pragma unroll 4
    for (int j = jbeg; j < jend; ++j) {
        float iw = (fminf(x2, gx2[j]) - fmaxf(x1, gx1[j])) + 1.0f;
        float ih = (fminf(y2, gy2[j]) - fmaxf(y1, gy1[j])) + 1.0f;
        iw = fmaxf(iw, 0.0f);
        ih = fmaxf(ih, 0.0f);
        float inter = iw * ih;
        // IEEE-correct division: bit-matches numpy; strict > = first-occurrence
        float iou = inter / ((A + gar[j]) - inter);
        if (iou > mx) { mx = iou; am = j; }
    }
    smx[w][lane] = mx; sam[w][lane] = am;
    __syncthreads();

    if (t < 64) {                      // wave 0 combines + counts
        float m0 = smx[0][t]; int a0 = sam[0][t];
#pragma unroll
        for (int ww = 1; ww < 4; ++ww) {
            float m2 = smx[ww][t];
            if (m2 > m0) { m0 = m2; a0 = sam[ww][t]; }
        }
        int cls = 0;
        const int i2 = blockIdx.x * 64 + t;
        if (i2 < N) {
            if (m0 >= 0.5f) cls = 1;
            else if (m0 >= 0.1f) cls = 2;
            code[i2] = (uint16_t)((a0 << 2) | cls);
        }
        unsigned long long mF = __ballot(cls == 1);
        unsigned long long mB = __ballot(cls == 2);
        if (t == 0) { blkF[blockIdx.x] = __popcll(mF); blkB[blockIdx.x] = __popcll(mB); }
    }
}

// ---------------- Kernel 2: ordered first-k selection + epilogue ----------------
// Single block, 256 threads. Parallel prefix over per-chunk counts -> each
// contributing chunk's global fg/bg base; compacted worklist processed by all
// 4 waves concurrently (disjoint keep slots). Then 128-thread epilogue.
__global__ __launch_bounds__(256) void ptl_select_emit(
    const float* __restrict__ all_rois, const float* __restrict__ gt,
    const uint16_t* __restrict__ code,
    const int* __restrict__ blkF, const int* __restrict__ blkB,
    int R, int G, int N, int nch,
    float* __restrict__ out)
{
#pragma clang fp contract(off)
    __shared__ int sF[MAXCH], sB[MAXCH];
    __shared__ int EF[MAXCH], EB[MAXCH];
    __shared__ int tsF[256], tsB[256];
    __shared__ int keep[OUT_ROIS];
    __shared__ int nwork;
    __shared__ unsigned short work[MAXCH];
    const int t = threadIdx.x;

    for (int c = t; c < nch; c += 256) { sF[c] = blkF[c]; sB[c] = blkB[c]; }
    for (int c = nch + t; c < MAXCH; c += 256) { sF[c] = 0; sB[c] = 0; }
    if (t < OUT_ROIS) keep[t] = 0;    // reference: unfilled slots index roi 0
    if (t == 0) nwork = 0;
    __syncthreads();

    // per-thread sums over 9 chunks
    const int c0 = t * (MAXCH / 256);
    int baseF = 0, baseB = 0;
#pragma unroll
    for (int k = 0; k < MAXCH / 256; ++k) { baseF += sF[c0 + k]; baseB += sB[c0 + k]; }
    tsF[t] = baseF; tsB[t] = baseB;
    __syncthreads();
    // Hillis-Steele inclusive scan over 256 thread-sums
    for (int d = 1; d < 256; d <<= 1) {
        int vF = (t >= d) ? tsF[t - d] : 0;
        int vB = (t >= d) ? tsB[t - d] : 0;
        __syncthreads();
        tsF[t] += vF; tsB[t] += vB;
        __syncthreads();
    }
    const int tf = tsF[255], tb = tsB[255];
    const int num_fg = tf < FG_MAX ? tf : FG_MAX;
    {
        // nothing
    }
    const int rem = OUT_ROIS - num_fg;
    const int num_bg = tb < rem ? tb : rem;

    // write back exclusive prefixes; build worklist of contributing chunks
    int rF = tsF[t] - baseF, rB = tsB[t] - baseB;
#pragma unroll
    for (int k = 0; k < MAXCH / 256; ++k) {
        const int c = c0 + k;
        const int cf = sF[c], cb = sB[c];
        EF[c] = rF; EB[c] = rB;
        const bool need = ((cf > 0 && rF < num_fg) || (cb > 0 && rB < num_bg)) && (c < nch);
        if (need) { int p = atomicAdd(&nwork, 1); work[p] = (unsigned short)c; }
        rF += cf; rB += cb;
    }
    __syncthreads();

    const int w = t >> 6, lane = t & 63;
    const unsigned long long lowmask = (1ull << lane) - 1ull;
    const int nw = nwork;
    for (int idx = w; idx < nw; idx += 4) {
        const int c = work[idx];
        const int i = c * 64 + lane;
        const int cd = (i < N) ? (int)(code[i] & 3) : 0;
        unsigned long long mF = __ballot(cd == 1);
        unsigned long long mB = __ballot(cd == 2);
        const int pF = EF[c] + __popcll(mF & lowmask);
        const int pB = EB[c] + __popcll(mB & lowmask);
        if (cd == 1 && pF < num_fg) keep[pF] = i;
        if (cd == 2 && pB < num_bg) keep[num_fg + pB] = i;
    }
    __syncthreads();

    if (t < OUT_ROIS) {
        const int s = t;
        const int k = keep[s];
        const bool isfg = s < num_fg;
        float x1, y1, x2, y2;
        if (k < R) {
            const float* p = all_rois + (size_t)k * 5;
            x1 = p[1]; y1 = p[2]; x2 = p[3]; y2 = p[4];
        } else {
            const float* p = gt + (size_t)(k - R) * 6;
            x1 = p[0]; y1 = p[1]; x2 = p[2]; y2 = p[3];
        }
        const int amax = (int)(code[k] >> 2);
        const float* g = gt + (size_t)amax * 6;
        const float gx1v = g[0], gy1v = g[1], gx2v = g[2], gy2v = g[3];
        const float label = isfg ? g[4] : 0.0f;
        const float pid = isfg ? g[5] : BG_PID_F;

        // rois [128,5] @ 0
        float* ro = out + (size_t)s * 5;
        ro[0] = 0.0f; ro[1] = x1; ro[2] = y1; ro[3] = x2; ro[4] = y2;
        // labels [128] @ 640, pids [128] @ 768 (int-valued floats)
        out[640 + s] = (float)(int)label;
        out[768 + s] = (float)(int)pid;

        // bbox_transform + normalize, matching reference op order
        const float ew = (x2 - x1) + 1.0f, eh = (y2 - y1) + 1.0f;
        const float ecx = x1 + 0.5f * ew, ecy = y1 + 0.5f * eh;
        const float gw = (gx2v - gx1v) + 1.0f, gh = (gy2v - gy1v) + 1.0f;
        const float gcx = gx1v + 0.5f * gw, gcy = gy1v + 0.5f * gh;
        float tv[4];
        tv[0] = ((gcx - ecx) / ew) / 0.1f;
        tv[1] = ((gcy - ecy) / eh) / 0.1f;
        tv[2] = logf(gw / ew) / 0.2f;
        tv[3] = logf(gh / eh) / 0.2f;

        const int cls = (int)roundf(label);
        const float on = (label > 0.0f) ? 1.0f : 0.0f;

        float* bt = out + 896  + (size_t)s * 8;
        float* bi = out + 1920 + (size_t)s * 8;
        float* bo = out + 2944 + (size_t)s * 8;
#pragma unroll
        for (int cc = 0; cc < 2; ++cc) {
            const float sel = (cc == cls) ? on : 0.0f;
#pragma unroll
            for (int j = 0; j < 4; ++j) {
                bt[cc * 4 + j] = sel * tv[j];
                bi[cc * 4 + j] = sel;
                bo[cc * 4 + j] = sel;
            }
        }
    }
}

extern "C" void kernel_launch(void* const* d_in, const int* in_sizes, int n_in,
                              void* d_out, int out_size, void* d_ws, size_t ws_size,
                              hipStream_t stream) {
    const float* all_rois = (const float*)d_in[0];
    const float* gt       = (const float*)d_in[1];
    const int R = in_sizes[0] / 5;
    const int G = in_sizes[1] / 6;
    const int N = R + G;
    const int nch = (N + 63) / 64;     // 2052 for this problem (<= MAXCH)

    uint16_t* code = (uint16_t*)d_ws;
    size_t codeBytes = (((size_t)N * 2) + 3) & ~(size_t)3;
    int* blkF = (int*)((char*)d_ws + codeBytes);
    int* blkB = blkF + nch;
    float* out = (float*)d_out;

    ptl_classify<<<nch, 256, 0, stream>>>(all_rois, gt, R, G, N, code, blkF, blkB);
    ptl_select_emit<<<1, 256, 0, stream>>>(all_rois, gt, code, blkF, blkB, R, G, N, nch, out);
}